// Round 3
// baseline (84.236 us; speedup 1.0000x reference)
//
#include <hip/hip_runtime.h>

#define HWC 16384      // H*W
#define WD  128
#define NC  64
#define EPSV 1e-6f

// ---------------- Kernel 1: head 1x1 conv + ReLU -> h (in d_ws) -------------
// grid 1024 x 512. Block = (b,y,seg): one 64-px row segment, all 64 out ch.
// Wave wv computes out-channels [8wv,8wv+8) for pixel `lane`.
__global__ __launch_bounds__(512) void k_head(const float* __restrict__ x,
                                              const float* __restrict__ Wh,
                                              float* __restrict__ h) {
  __shared__ float xs[64 * 64];   // [c][px]
  __shared__ float ws[64 * 64];   // [o][c] row-major as in memory
  const int t = threadIdx.x;
  const int lane = t & 63;
  const int wv = t >> 6;
  const int bid = blockIdx.x;
  const int seg = bid & 1, y = (bid >> 1) & 127, b = bid >> 8;
  const int w0 = seg * 64;
  const int cb = wv * 8;

  { // stage weights (4096 floats) as float4
    const float4* __restrict__ Wv = (const float4*)Wh;
    float4* wsv = (float4*)ws;
    wsv[t] = Wv[t];
    wsv[t + 512] = Wv[t + 512];
  }
  { // stage x tile: wave wv loads channels [8wv,8wv+8), coalesced per channel
    const float* xb = x + (size_t)b * (NC * HWC) + (size_t)y * WD + w0;
#pragma unroll
    for (int i = 0; i < 8; ++i)
      xs[(cb + i) * 64 + lane] = xb[(size_t)(cb + i) * HWC + lane];
  }
  __syncthreads();

  float acc[8];
#pragma unroll
  for (int j = 0; j < 8; ++j) acc[j] = 0.f;

#pragma unroll 4
  for (int c = 0; c < 64; c += 4) {
    const float xv0 = xs[(c + 0) * 64 + lane];
    const float xv1 = xs[(c + 1) * 64 + lane];
    const float xv2 = xs[(c + 2) * 64 + lane];
    const float xv3 = xs[(c + 3) * 64 + lane];
#pragma unroll
    for (int j = 0; j < 8; ++j) {
      const float4 w4 = *(const float4*)&ws[(cb + j) * 64 + c];  // wave-uniform b128 broadcast
      acc[j] += w4.x * xv0 + w4.y * xv1 + w4.z * xv2 + w4.w * xv3;
    }
  }
  float* hb = h + (size_t)b * (NC * HWC) + (size_t)y * WD + w0 + lane;
#pragma unroll
  for (int j = 0; j < 8; ++j) {
    const float v = acc[j];
    hb[(size_t)(cb + j) * HWC] = v > 0.f ? v : 0.f;
  }
}

// ------- Kernel 2: fused per-pixel NMF + tail 1x1 conv + residual -----------
// grid 1024 x 512. Block = (b,y,seg) 64-px segment.
// NMF phase: lane owns (channel-group cg = lane&7 -> 8 channels) x (pixel
// px = 8*wv + (lane>>3)); per-pixel reduce = shfl_xor butterfly over cg lanes.
// Tail phase: wave wv -> out channels [8wv,8wv+8), lane = px; UV via LDS.
__global__ __launch_bounds__(512) void k_nmf_tail(const float* __restrict__ h,
                                                  const float* __restrict__ x,
                                                  const float* __restrict__ Wt,
                                                  float* __restrict__ out) {
  __shared__ float uvs[64 * 66];  // [px][c], pad 66 (b64-aligned, 2-way max)
  __shared__ float ws[64 * 64];   // [c][o] row-major as in memory
  const int t = threadIdx.x;
  const int lane = t & 63;
  const int wv = t >> 6;
  const int bid0 = blockIdx.x;
  const int bid = ((bid0 & 7) << 7) | (bid0 >> 3);  // XCD chunk swizzle (1024 wgs, bijective)
  const int seg = bid & 1, y = (bid >> 1) & 127, b = bid >> 8;
  const int w0 = seg * 64;

  { // stage Wt
    const float4* __restrict__ Wv = (const float4*)Wt;
    float4* wsv = (float4*)ws;
    wsv[t] = Wv[t];
    wsv[t + 512] = Wv[t + 512];
  }

  const int pxl = lane >> 3;        // pixel within wave, 0..7
  const int px = (wv << 3) | pxl;   // block-local pixel 0..63
  const int cg = lane & 7;          // channel group
  const int wcol = w0 + px;
  int aw = wcol - 2; if (aw < 0) aw = 0;        // clamped left-tap col
  int bw = wcol + 2; if (bw > 127) bw = 127;    // clamped right-tap col
  int rowoff[3];
  rowoff[0] = (y >= 2 ? y - 2 : 0) * WD;
  rowoff[1] = y * WD;
  rowoff[2] = (y <= 125 ? y + 2 : 127) * WD;

  const float* hb = h + (size_t)b * (NC * HWC);
  const int c0 = cg * 8;

  float S = 0.f, sumk[9], A[9];
#pragma unroll
  for (int k = 0; k < 9; ++k) { sumk[k] = 0.f; A[k] = 0.f; }

  // ---- Pass 1: partial S, sumk, A over this lane's 8 channels ----
#pragma unroll
  for (int i = 0; i < 8; ++i) {
    const float* hc = hb + (size_t)(c0 + i) * HWC;
    float tap[9];
#pragma unroll
    for (int r = 0; r < 3; ++r) {
      const float av = hc[rowoff[r] + aw];
      const float bv = hc[rowoff[r] + bw];
      const float mda = __shfl(av, lane + 16);  // px+2's left tap == col px
      const float mdb = __shfl(bv, lane - 16);  // px-2's right tap == col px
      tap[3 * r + 0] = av;
      tap[3 * r + 1] = (pxl < 6) ? mda : mdb;
      tap[3 * r + 2] = bv;
    }
    float m = 0.f;
#pragma unroll
    for (int k = 0; k < 9; ++k) m += tap[k];
    m *= (1.f / 9.f);
    S += m * m;
#pragma unroll
    for (int k = 0; k < 9; ++k) { sumk[k] += tap[k]; A[k] += m * tap[k]; }
  }

  // ---- butterfly reduce over the 8 channel-group lanes (xor 1,2,4) ----
#pragma unroll
  for (int d = 1; d <= 4; d <<= 1) {
    S += __shfl_xor(S, d);
#pragma unroll
    for (int k = 0; k < 9; ++k) sumk[k] += __shfl_xor(sumk[k], d);
#pragma unroll
    for (int k = 0; k < 9; ++k) A[k] += __shfl_xor(A[k], d);
  }

  float Vk[9], T = 0.f;
#pragma unroll
  for (int k = 0; k < 9; ++k) {
    const float nk = sumk[k] * (1.f / 64.f);
    Vk[k] = nk * (A[k] / (3.f * nk * S + EPSV));
    T += Vk[k] * Vk[k];
  }
  const float V4 = Vk[4];

  // ---- Pass 2: reload taps, B, U; write UV into LDS ----
#pragma unroll
  for (int i = 0; i < 8; ++i) {
    const float* hc = hb + (size_t)(c0 + i) * HWC;
    float tap[9];
#pragma unroll
    for (int r = 0; r < 3; ++r) {
      const float av = hc[rowoff[r] + aw];
      const float bv = hc[rowoff[r] + bw];
      const float mda = __shfl(av, lane + 16);
      const float mdb = __shfl(bv, lane - 16);
      tap[3 * r + 0] = av;
      tap[3 * r + 1] = (pxl < 6) ? mda : mdb;
      tap[3 * r + 2] = bv;
    }
    float m = 0.f, Bc = 0.f;
#pragma unroll
    for (int k = 0; k < 9; ++k) { m += tap[k]; Bc += tap[k] * Vk[k]; }
    m *= (1.f / 9.f);
    const float Uc = m * (Bc / (3.f * m * T + EPSV));
    uvs[px * 66 + c0 + i] = 3.f * Uc * V4;
  }
  __syncthreads();

  // ---- Tail 1x1 conv + residual ----
  float acc[8];
#pragma unroll
  for (int j = 0; j < 8; ++j) acc[j] = 0.f;
  const float* uvp = &uvs[lane * 66];
  const int cb = wv * 8;
#pragma unroll 4
  for (int o = 0; o < 64; o += 4) {
    const float2 u01 = *(const float2*)&uvp[o];
    const float2 u23 = *(const float2*)&uvp[o + 2];
#pragma unroll
    for (int j = 0; j < 8; ++j) {
      const float4 w4 = *(const float4*)&ws[(cb + j) * 64 + o];  // wave-uniform b128
      acc[j] += w4.x * u01.x + w4.y * u01.y + w4.z * u23.x + w4.w * u23.y;
    }
  }
  const size_t base = (size_t)b * (NC * HWC) + (size_t)y * WD + w0 + lane;
  const float* xb = x + base;
  float* ob = out + base;
#pragma unroll
  for (int j = 0; j < 8; ++j) {
    const size_t off = (size_t)(cb + j) * HWC;
    ob[off] = acc[j] + xb[off];
  }
}

extern "C" void kernel_launch(void* const* d_in, const int* in_sizes, int n_in,
                              void* d_out, int out_size, void* d_ws, size_t ws_size,
                              hipStream_t stream) {
  const float* x  = (const float*)d_in[0];
  const float* Wh = (const float*)d_in[1];
  const float* Wt = (const float*)d_in[2];
  float* out = (float*)d_out;
  float* h   = (float*)d_ws;   // 4*64*128*128*4 = 16.78 MB scratch

  k_head<<<1024, 512, 0, stream>>>(x, Wh, h);
  k_nmf_tail<<<1024, 512, 0, stream>>>(h, x, Wt, out);
}

// Round 4
// 59.050 us; speedup vs baseline: 1.4265x; 1.4265x over previous
//
#include <hip/hip_runtime.h>

#define HWC 16384      // H*W
#define WD  128
#define NC  64
#define EPSV 1e-6f

// ---------------- Kernel 1: head 1x1 conv + ReLU -> h (in d_ws) -------------
// grid 512 (b,y): one full 128-px row. 512 thr = 8 waves.
// Thread computes 8 out-channels x 2 pixels (lane, lane+64).
__global__ __launch_bounds__(512) void k_head(const float* __restrict__ x,
                                              const float* __restrict__ Wh,
                                              float* __restrict__ h) {
  __shared__ float xs[64 * 128];  // [c][px]
  __shared__ float ws[64 * 64];   // [oc][c] row-major as in memory
  const int t = threadIdx.x;
  const int lane = t & 63;
  const int wv = t >> 6;
  const int bid = blockIdx.x;
  const int y = bid & 127, b = bid >> 7;
  const int cb = wv * 8;

  { // stage weights (4096 floats) as float4
    const float4* __restrict__ Wv = (const float4*)Wh;
    float4* wsv = (float4*)ws;
    wsv[t] = Wv[t];
    wsv[t + 512] = Wv[t + 512];
  }
  { // stage x row: wave wv loads channels [8wv,8wv+8), coalesced
    const float* xb = x + (size_t)b * (NC * HWC) + (size_t)y * WD;
#pragma unroll
    for (int i = 0; i < 8; ++i) {
      const int c = cb + i;
      xs[c * 128 + lane]      = xb[(size_t)c * HWC + lane];
      xs[c * 128 + 64 + lane] = xb[(size_t)c * HWC + 64 + lane];
    }
  }
  __syncthreads();

  float acc0[8], acc1[8];
#pragma unroll
  for (int j = 0; j < 8; ++j) { acc0[j] = 0.f; acc1[j] = 0.f; }

#pragma unroll 4
  for (int c = 0; c < 64; c += 4) {
    const float a0 = xs[(c + 0) * 128 + lane];
    const float a1 = xs[(c + 1) * 128 + lane];
    const float a2 = xs[(c + 2) * 128 + lane];
    const float a3 = xs[(c + 3) * 128 + lane];
    const float b0 = xs[(c + 0) * 128 + 64 + lane];
    const float b1 = xs[(c + 1) * 128 + 64 + lane];
    const float b2 = xs[(c + 2) * 128 + 64 + lane];
    const float b3 = xs[(c + 3) * 128 + 64 + lane];
#pragma unroll
    for (int j = 0; j < 8; ++j) {
      const float4 w4 = *(const float4*)&ws[(cb + j) * 64 + c];  // wave-uniform b128 broadcast
      acc0[j] += w4.x * a0 + w4.y * a1 + w4.z * a2 + w4.w * a3;
      acc1[j] += w4.x * b0 + w4.y * b1 + w4.z * b2 + w4.w * b3;
    }
  }
  float* hb = h + (size_t)b * (NC * HWC) + (size_t)y * WD;
#pragma unroll
  for (int j = 0; j < 8; ++j) {
    const float v0 = acc0[j], v1 = acc1[j];
    hb[(size_t)(cb + j) * HWC + lane]      = v0 > 0.f ? v0 : 0.f;
    hb[(size_t)(cb + j) * HWC + 64 + lane] = v1 > 0.f ? v1 : 0.f;
  }
}

// ------- Kernel 2: fused per-pixel NMF + tail 1x1 conv + residual -----------
// grid 1024 (b,y,seg): one 64-px row segment. 256 thr = 4 waves.
// NMF: lane = pixel (coalesced loads), wave wv owns channels [16wv,16wv+16);
// cross-wave reduce of 19 partials via stride-21 LDS. Tail: wave wv -> out
// channels [16wv,16wv+16), UV tile via LDS (unioned with reduce buffer).
__global__ __launch_bounds__(256) void k_nmf_tail(const float* __restrict__ h,
                                                  const float* __restrict__ x,
                                                  const float* __restrict__ Wt,
                                                  float* __restrict__ out) {
  __shared__ float ws[64 * 64];     // [c][o] row-major as in memory
  __shared__ float red[256 * 21];   // union: reduce buf / uv tile [px*66+c]
  float* uvs = red;                 // 64*66 = 4224 <= 5376

  const int t = threadIdx.x;
  const int lane = t & 63;
  const int wv = t >> 6;
  const int bid0 = blockIdx.x;
  const int bid = ((bid0 & 7) << 7) | (bid0 >> 3);  // XCD chunk swizzle, bijective
  const int seg = bid & 1, y = (bid >> 1) & 127, b = bid >> 8;
  const int w0 = seg * 64;

  { // stage Wt
    const float4* __restrict__ Wv = (const float4*)Wt;
    float4* wsv = (float4*)ws;
    wsv[t] = Wv[t];
    wsv[t + 256] = Wv[t + 256];
    wsv[t + 512] = Wv[t + 512];
    wsv[t + 768] = Wv[t + 768];
  }

  const int wcol = w0 + lane;
  int aw = wcol - 2; if (aw < 0) aw = 0;        // clamped left-tap col
  int bw = wcol + 2; if (bw > 127) bw = 127;    // clamped right-tap col
  int rowoff[3];
  rowoff[0] = (y >= 2 ? y - 2 : 0) * WD;
  rowoff[1] = y * WD;
  rowoff[2] = (y <= 125 ? y + 2 : 127) * WD;

  const float* hb = h + (size_t)b * (NC * HWC);
  const int c0 = wv * 16;

  float S = 0.f, sumk[9], A[9], mreg[16];
#pragma unroll
  for (int k = 0; k < 9; ++k) { sumk[k] = 0.f; A[k] = 0.f; }

  // ---- Pass 1: partial S, sumk, A over this wave's 16 channels ----
#pragma unroll 4
  for (int i = 0; i < 16; ++i) {
    const float* hc = hb + (size_t)(c0 + i) * HWC;
    float tap[9];
#pragma unroll
    for (int r = 0; r < 3; ++r) {
      tap[3 * r + 0] = hc[rowoff[r] + aw];
      tap[3 * r + 1] = hc[rowoff[r] + wcol];
      tap[3 * r + 2] = hc[rowoff[r] + bw];
    }
    float m = 0.f;
#pragma unroll
    for (int k = 0; k < 9; ++k) m += tap[k];
    m *= (1.f / 9.f);
    mreg[i] = m;
    S += m * m;
#pragma unroll
    for (int k = 0; k < 9; ++k) { sumk[k] += tap[k]; A[k] += m * tap[k]; }
  }

  // ---- cross-wave reduce via LDS (stride 21: conflict-free) ----
  {
    const int rb = t * 21;
    red[rb + 0] = S;
#pragma unroll
    for (int k = 0; k < 9; ++k) red[rb + 1 + k] = sumk[k];
#pragma unroll
    for (int k = 0; k < 9; ++k) red[rb + 10 + k] = A[k];
  }
  __syncthreads();
  float Sf = 0.f, sumkf[9], Af[9];
#pragma unroll
  for (int k = 0; k < 9; ++k) { sumkf[k] = 0.f; Af[k] = 0.f; }
#pragma unroll
  for (int v = 0; v < 4; ++v) {
    const int rb = (v * 64 + lane) * 21;
    Sf += red[rb + 0];
#pragma unroll
    for (int k = 0; k < 9; ++k) sumkf[k] += red[rb + 1 + k];
#pragma unroll
    for (int k = 0; k < 9; ++k) Af[k] += red[rb + 10 + k];
  }
  __syncthreads();   // protect red before uv overwrite

  float Vk[9], T = 0.f;
#pragma unroll
  for (int k = 0; k < 9; ++k) {
    const float nk = sumkf[k] * (1.f / 64.f);
    Vk[k] = nk * (Af[k] / (3.f * nk * Sf + EPSV));
    T += Vk[k] * Vk[k];
  }
  const float V4 = Vk[4];

  // ---- Pass 2: reload taps (L1-hot), B, U; write UV into LDS ----
#pragma unroll 4
  for (int i = 0; i < 16; ++i) {
    const float* hc = hb + (size_t)(c0 + i) * HWC;
    float tap[9];
#pragma unroll
    for (int r = 0; r < 3; ++r) {
      tap[3 * r + 0] = hc[rowoff[r] + aw];
      tap[3 * r + 1] = hc[rowoff[r] + wcol];
      tap[3 * r + 2] = hc[rowoff[r] + bw];
    }
    float Bc = 0.f;
#pragma unroll
    for (int k = 0; k < 9; ++k) Bc += tap[k] * Vk[k];
    const float m = mreg[i];
    const float Uc = m * (Bc / (3.f * m * T + EPSV));
    uvs[lane * 66 + c0 + i] = 3.f * Uc * V4;
  }
  __syncthreads();

  // ---- Tail 1x1 conv + residual ----
  float acc[16];
#pragma unroll
  for (int j = 0; j < 16; ++j) acc[j] = 0.f;
  const float* uvp = &uvs[lane * 66];
  const int ocb = wv * 16;
#pragma unroll 4
  for (int o = 0; o < 64; o += 4) {
    const float2 u01 = *(const float2*)&uvp[o];
    const float2 u23 = *(const float2*)&uvp[o + 2];
#pragma unroll
    for (int j = 0; j < 16; ++j) {
      const float4 w4 = *(const float4*)&ws[(ocb + j) * 64 + o];  // wave-uniform b128
      acc[j] += w4.x * u01.x + w4.y * u01.y + w4.z * u23.x + w4.w * u23.y;
    }
  }
  const size_t base = (size_t)b * (NC * HWC) + (size_t)y * WD + w0 + lane;
  const float* xb = x + base;
  float* ob = out + base;
#pragma unroll
  for (int j = 0; j < 16; ++j) {
    const size_t off = (size_t)(ocb + j) * HWC;
    ob[off] = acc[j] + xb[off];
  }
}

extern "C" void kernel_launch(void* const* d_in, const int* in_sizes, int n_in,
                              void* d_out, int out_size, void* d_ws, size_t ws_size,
                              hipStream_t stream) {
  const float* x  = (const float*)d_in[0];
  const float* Wh = (const float*)d_in[1];
  const float* Wt = (const float*)d_in[2];
  float* out = (float*)d_out;
  float* h   = (float*)d_ws;   // 4*64*128*128*4 = 16.78 MB scratch

  k_head<<<512, 512, 0, stream>>>(x, Wh, h);
  k_nmf_tail<<<1024, 256, 0, stream>>>(h, x, Wt, out);
}

// Round 5
// 58.330 us; speedup vs baseline: 1.4441x; 1.0123x over previous
//
#include <hip/hip_runtime.h>

#define HWC 16384      // H*W
#define WD  128
#define NC  64
#define EPSV 1e-6f

typedef __attribute__((ext_vector_type(8))) short bf16x8;
typedef __attribute__((ext_vector_type(4))) float f32x4;

__device__ __forceinline__ unsigned short f2bf(float f) {
  unsigned u = __builtin_bit_cast(unsigned, f);
  u = (u + 0x7FFFu + ((u >> 16) & 1u)) >> 16;   // RNE
  return (unsigned short)u;
}
__device__ __forceinline__ float bf2f(unsigned short h) {
  unsigned u = ((unsigned)h) << 16;
  return __builtin_bit_cast(float, u);
}
// XOR swizzle for [64][64] bf16 tiles (128 B rows): spreads b128 frag reads.
__device__ __forceinline__ int swz(int row, int colbytes) {
  return ((row << 7) + colbytes) ^ ((row & 7) << 4);
}

// ---------------- Kernel 1: head 1x1 conv (MFMA) + ReLU -> h bf16 ----------
// grid 1024 (b,y,seg): 64-px segment. 256 thr = 4 waves.
// M=oc (wave wv -> rows 16wv..+16), N=px 64 (4 tiles), K=c 64 (2 steps).
__global__ __launch_bounds__(256) void k_head(const float* __restrict__ x,
                                              const float* __restrict__ Wh,
                                              unsigned short* __restrict__ h) {
  __shared__ unsigned short whs[4096];  // Wh bf16 [o][c], swizzled
  __shared__ unsigned short xt[4096];   // x^T bf16 [px][c], swizzled
  const int t = threadIdx.x, lane = t & 63, wv = t >> 6;
  const int bid = blockIdx.x;
  const int seg = bid & 1, y = (bid >> 1) & 127, b = bid >> 8;
  const int w0 = seg << 6;

#pragma unroll
  for (int i = 0; i < 16; ++i) {
    const int idx = i * 256 + t;
    const int o = idx >> 6, c = idx & 63;
    *(unsigned short*)((char*)whs + swz(o, c * 2)) = f2bf(Wh[idx]);
  }
  {
    const float* xb = x + (size_t)b * (NC * HWC) + (size_t)y * WD + w0;
    const int c0 = wv << 4;
#pragma unroll
    for (int q = 0; q < 4; ++q) {
      unsigned long long pk = 0;
#pragma unroll
      for (int u = 0; u < 4; ++u) {
        const unsigned short v = f2bf(xb[(size_t)(c0 + q * 4 + u) * HWC + lane]);
        pk |= (unsigned long long)v << (16 * u);
      }
      *(unsigned long long*)((char*)xt + swz(lane, (c0 + q * 4) * 2)) = pk;
    }
  }
  __syncthreads();

  const int l15 = lane & 15, kg = lane >> 4;
  const int mrow = (wv << 4) + l15;
  const bf16x8 a0 = *(const bf16x8*)((char*)whs + swz(mrow, kg * 16));
  const bf16x8 a1 = *(const bf16x8*)((char*)whs + swz(mrow, 64 + kg * 16));
  const f32x4 z = {0.f, 0.f, 0.f, 0.f};
  unsigned short* hb = h + (size_t)b * (NC * HWC) + (size_t)y * WD + w0;
#pragma unroll
  for (int nt = 0; nt < 4; ++nt) {
    const int px = (nt << 4) + l15;
    const bf16x8 b0 = *(const bf16x8*)((char*)xt + swz(px, kg * 16));
    const bf16x8 b1 = *(const bf16x8*)((char*)xt + swz(px, 64 + kg * 16));
    f32x4 acc = __builtin_amdgcn_mfma_f32_16x16x32_bf16(a0, b0, z, 0, 0, 0);
    acc = __builtin_amdgcn_mfma_f32_16x16x32_bf16(a1, b1, acc, 0, 0, 0);
#pragma unroll
    for (int j = 0; j < 4; ++j) {
      const int o = (wv << 4) + kg * 4 + j;   // D: row=(lane>>4)*4+j, col=l15
      float v = acc[j];
      v = v > 0.f ? v : 0.f;
      hb[(size_t)o * HWC + px] = f2bf(v);
    }
  }
}

// ------- Kernel 2: fused NMF (f32, LDS-staged bf16 taps) + MFMA tail -------
// grid 1024 (b,y,seg). 256 thr = 4 waves. NMF: lane=px, wave wv owns
// channels [16wv,+16); reduce via LDS; tail: M=c_out, N=px, K=o.
__global__ __launch_bounds__(256) void k_nmf_tail(const unsigned short* __restrict__ h,
                                                  const float* __restrict__ x,
                                                  const float* __restrict__ Wt,
                                                  float* __restrict__ out) {
  __shared__ unsigned short hs[64 * 216];  // h tile bf16 [c][r=3][72], 27648 B
  __shared__ unsigned short wts[4096];     // Wt bf16 [c][o], swizzled, 8192 B
  __shared__ float un[4032];               // union: redf(16128B) / uvb(8192B) / bcast@f32[2048..2688)
  unsigned short* uvb = (unsigned short*)un;  // UV bf16 [px][o], swizzled
  float* redf = un;
  float* bcast = un + 2048;

  const int t = threadIdx.x, lane = t & 63, wv = t >> 6;
  const int bid0 = blockIdx.x;
  const int bid = ((bid0 & 7) << 7) | (bid0 >> 3);  // XCD swizzle, bijective (1024%8==0)
  const int seg = bid & 1, y = (bid >> 1) & 127, b = bid >> 8;
  const int w0 = seg << 6;

#pragma unroll
  for (int i = 0; i < 16; ++i) {
    const int idx = i * 256 + t;
    const int c = idx >> 6, o = idx & 63;
    *(unsigned short*)((char*)wts + swz(c, o * 2)) = f2bf(Wt[idx]);
  }

  int rowoff[3];
  rowoff[0] = (y >= 2 ? y - 2 : 0) * WD;
  rowoff[1] = y * WD;
  rowoff[2] = (y <= 125 ? y + 2 : 127) * WD;
  const int c0 = wv << 4;
  { // stage h tile: cols w0-2 .. w0+65 (hs idx i <-> col w0-2+i, clamped)
    const unsigned short* hg = h + (size_t)b * (NC * HWC);
    int colA = w0 - 2 + lane; if (colA < 0) colA = 0;
    int colB = w0 + 62 + (lane & 3); if (colB > 127) colB = 127;
#pragma unroll
    for (int i = 0; i < 16; ++i) {
      const unsigned short* hc = hg + (size_t)(c0 + i) * HWC;
      const int hbase = (c0 + i) * 216;
#pragma unroll
      for (int r = 0; r < 3; ++r) {
        hs[hbase + r * 72 + lane] = hc[rowoff[r] + colA];
        if (lane < 4) hs[hbase + r * 72 + 64 + lane] = hc[rowoff[r] + colB];
      }
    }
  }
  __syncthreads();

  // ---- Pass 1: S, sumk[9], A[9] partials over wave's 16 channels ----
  float S = 0.f, sumk[9], A[9], mreg[16];
#pragma unroll
  for (int k = 0; k < 9; ++k) { sumk[k] = 0.f; A[k] = 0.f; }
#pragma unroll
  for (int i = 0; i < 16; ++i) {
    const int hbase = (c0 + i) * 216 + lane;
    float tap[9];
#pragma unroll
    for (int r = 0; r < 3; ++r) {
      tap[3 * r + 0] = bf2f(hs[hbase + r * 72]);      // col px-2
      tap[3 * r + 1] = bf2f(hs[hbase + r * 72 + 2]);  // col px
      tap[3 * r + 2] = bf2f(hs[hbase + r * 72 + 4]);  // col px+2
    }
    float m = 0.f;
#pragma unroll
    for (int k = 0; k < 9; ++k) m += tap[k];
    m *= (1.f / 9.f);
    mreg[i] = m;
    S += m * m;
#pragma unroll
    for (int k = 0; k < 9; ++k) { sumk[k] += tap[k]; A[k] += m * tap[k]; }
  }

  // ---- cross-wave reduce: waves 1-3 write, wave 0 combines + broadcasts ----
  if (wv != 0) {
    const int rb = (t - 64) * 21;
    redf[rb] = S;
#pragma unroll
    for (int k = 0; k < 9; ++k) redf[rb + 1 + k] = sumk[k];
#pragma unroll
    for (int k = 0; k < 9; ++k) redf[rb + 10 + k] = A[k];
  }
  __syncthreads();
  float Vk[9], T = 0.f;
  if (wv == 0) {
#pragma unroll
    for (int v = 0; v < 3; ++v) {
      const int rb = (v * 64 + lane) * 21;
      S += redf[rb];
#pragma unroll
      for (int k = 0; k < 9; ++k) sumk[k] += redf[rb + 1 + k];
#pragma unroll
      for (int k = 0; k < 9; ++k) A[k] += redf[rb + 10 + k];
    }
#pragma unroll
    for (int k = 0; k < 9; ++k) {
      const float nk = sumk[k] * (1.f / 64.f);
      Vk[k] = nk * (A[k] / (3.f * nk * S + EPSV));
      T += Vk[k] * Vk[k];
    }
#pragma unroll
    for (int k = 0; k < 9; ++k) bcast[lane * 10 + k] = Vk[k];
    bcast[lane * 10 + 9] = T;
  }
  __syncthreads();
  if (wv != 0) {
#pragma unroll
    for (int k = 0; k < 9; ++k) Vk[k] = bcast[lane * 10 + k];
    T = bcast[lane * 10 + 9];
  }
  const float V4 = Vk[4];

  // ---- Pass 2: B, U; write UV bf16 into swizzled LDS [px][o] ----
#pragma unroll
  for (int i = 0; i < 16; i += 2) {
    unsigned short pk[2];
#pragma unroll
    for (int u = 0; u < 2; ++u) {
      const int hbase = (c0 + i + u) * 216 + lane;
      float Bc = 0.f;
#pragma unroll
      for (int r = 0; r < 3; ++r) {
        Bc += bf2f(hs[hbase + r * 72])     * Vk[3 * r + 0];
        Bc += bf2f(hs[hbase + r * 72 + 2]) * Vk[3 * r + 1];
        Bc += bf2f(hs[hbase + r * 72 + 4]) * Vk[3 * r + 2];
      }
      const float m = mreg[i + u];
      const float Uc = m * (Bc / (3.f * m * T + EPSV));
      pk[u] = f2bf(3.f * Uc * V4);
    }
    const unsigned w32 = (unsigned)pk[0] | ((unsigned)pk[1] << 16);
    *(unsigned*)((char*)uvb + swz(lane, (c0 + i) * 2)) = w32;
  }
  __syncthreads();

  // ---- Tail MFMA: out[c2][px] = sum_o Wt[c2][o] * UV[px][o]  + residual ----
  const int l15 = lane & 15, kg = lane >> 4;
  const int mrow = (wv << 4) + l15;  // c_out row for A
  const bf16x8 a0 = *(const bf16x8*)((char*)wts + swz(mrow, kg * 16));
  const bf16x8 a1 = *(const bf16x8*)((char*)wts + swz(mrow, 64 + kg * 16));
  const f32x4 z = {0.f, 0.f, 0.f, 0.f};
  const size_t gb = (size_t)b * (NC * HWC) + (size_t)y * WD + w0;
#pragma unroll
  for (int nt = 0; nt < 4; ++nt) {
    const int px = (nt << 4) + l15;
    const bf16x8 b0 = *(const bf16x8*)((char*)uvb + swz(px, kg * 16));
    const bf16x8 b1 = *(const bf16x8*)((char*)uvb + swz(px, 64 + kg * 16));
    f32x4 acc = __builtin_amdgcn_mfma_f32_16x16x32_bf16(a0, b0, z, 0, 0, 0);
    acc = __builtin_amdgcn_mfma_f32_16x16x32_bf16(a1, b1, acc, 0, 0, 0);
#pragma unroll
    for (int j = 0; j < 4; ++j) {
      const int c2 = (wv << 4) + kg * 4 + j;
      const size_t off = gb + (size_t)c2 * HWC + px;
      out[off] = acc[j] + x[off];
    }
  }
}

extern "C" void kernel_launch(void* const* d_in, const int* in_sizes, int n_in,
                              void* d_out, int out_size, void* d_ws, size_t ws_size,
                              hipStream_t stream) {
  const float* x  = (const float*)d_in[0];
  const float* Wh = (const float*)d_in[1];
  const float* Wt = (const float*)d_in[2];
  float* out = (float*)d_out;
  unsigned short* h = (unsigned short*)d_ws;  // h in bf16: 8.39 MB scratch

  k_head<<<1024, 256, 0, stream>>>(x, Wh, h);
  k_nmf_tail<<<1024, 256, 0, stream>>>(h, x, Wt, out);
}

// Round 7
// 38.048 us; speedup vs baseline: 2.2139x; 1.5331x over previous
//
#include <hip/hip_runtime.h>

#define HWC 16384      // H*W
#define WD  128
#define NC  64
#define EPSV 1e-6f

typedef __attribute__((ext_vector_type(8))) short bf16x8;
typedef __attribute__((ext_vector_type(4))) float f32x4;

__device__ __forceinline__ unsigned short f2bf(float f) {
  unsigned u = __builtin_bit_cast(unsigned, f);
  u = (u + 0x7FFFu + ((u >> 16) & 1u)) >> 16;   // RNE
  return (unsigned short)u;
}
__device__ __forceinline__ float bf2f(unsigned short h) {
  unsigned u = ((unsigned)h) << 16;
  return __builtin_bit_cast(float, u);
}
// XOR swizzle for [64][64] bf16 tiles (128 B rows): spreads b128 frag reads.
__device__ __forceinline__ int swz(int row, int colbytes) {
  return ((row << 7) + colbytes) ^ ((row & 7) << 4);
}

// ---------------- Kernel 1: head 1x1 conv (MFMA) + ReLU -> h bf16 ----------
// grid 1024 (b,y,seg): 64-px segment. 256 thr = 4 waves. (unchanged from R5)
__global__ __launch_bounds__(256) void k_head(const float* __restrict__ x,
                                              const float* __restrict__ Wh,
                                              unsigned short* __restrict__ h) {
  __shared__ unsigned short whs[4096];  // Wh bf16 [o][c], swizzled
  __shared__ unsigned short xt[4096];   // x^T bf16 [px][c], swizzled
  const int t = threadIdx.x, lane = t & 63, wv = t >> 6;
  const int bid = blockIdx.x;
  const int seg = bid & 1, y = (bid >> 1) & 127, b = bid >> 8;
  const int w0 = seg << 6;

#pragma unroll
  for (int i = 0; i < 16; ++i) {
    const int idx = i * 256 + t;
    const int o = idx >> 6, c = idx & 63;
    *(unsigned short*)((char*)whs + swz(o, c * 2)) = f2bf(Wh[idx]);
  }
  {
    const float* xb = x + (size_t)b * (NC * HWC) + (size_t)y * WD + w0;
    const int c0 = wv << 4;
#pragma unroll
    for (int q = 0; q < 4; ++q) {
      unsigned long long pk = 0;
#pragma unroll
      for (int u = 0; u < 4; ++u) {
        const unsigned short v = f2bf(xb[(size_t)(c0 + q * 4 + u) * HWC + lane]);
        pk |= (unsigned long long)v << (16 * u);
      }
      *(unsigned long long*)((char*)xt + swz(lane, (c0 + q * 4) * 2)) = pk;
    }
  }
  __syncthreads();

  const int l15 = lane & 15, kg = lane >> 4;
  const int mrow = (wv << 4) + l15;
  const bf16x8 a0 = *(const bf16x8*)((char*)whs + swz(mrow, kg * 16));
  const bf16x8 a1 = *(const bf16x8*)((char*)whs + swz(mrow, 64 + kg * 16));
  const f32x4 z = {0.f, 0.f, 0.f, 0.f};
  unsigned short* hb = h + (size_t)b * (NC * HWC) + (size_t)y * WD + w0;
#pragma unroll
  for (int nt = 0; nt < 4; ++nt) {
    const int px = (nt << 4) + l15;
    const bf16x8 b0 = *(const bf16x8*)((char*)xt + swz(px, kg * 16));
    const bf16x8 b1 = *(const bf16x8*)((char*)xt + swz(px, 64 + kg * 16));
    f32x4 acc = __builtin_amdgcn_mfma_f32_16x16x32_bf16(a0, b0, z, 0, 0, 0);
    acc = __builtin_amdgcn_mfma_f32_16x16x32_bf16(a1, b1, acc, 0, 0, 0);
#pragma unroll
    for (int j = 0; j < 4; ++j) {
      const int o = (wv << 4) + kg * 4 + j;   // D: row=(lane>>4)*4+j, col=l15
      float v = acc[j];
      v = v > 0.f ? v : 0.f;
      hb[(size_t)o * HWC + px] = f2bf(v);
    }
  }
}

// ------- Kernel 2: fused NMF (global bf16 taps) + MFMA tail + residual -----
// grid 1024 (b,y,seg). 512 thr = 8 waves. lane = px (coalesced); wave wv owns
// channels [8wv,+8). Cross-wave reduce: 19 partials split ACROSS waves.
__global__ __launch_bounds__(512) void k_nmf_tail(const unsigned short* __restrict__ h,
                                                  const float* __restrict__ x,
                                                  const float* __restrict__ Wt,
                                                  float* __restrict__ out) {
  __shared__ float red[512 * 21];          // 43008 B; unioned with uvb after use
  __shared__ unsigned short wts[4096];     // Wt bf16 [c][o], swizzled, 8192 B
  unsigned short* uvb = (unsigned short*)red;  // UV bf16 [px][o], swizzled

  const int t = threadIdx.x, lane = t & 63, wv = t >> 6;
  const int bid0 = blockIdx.x;
  const int bid = ((bid0 & 7) << 7) | (bid0 >> 3);  // XCD swizzle, bijective (1024%8==0)
  const int seg = bid & 1, y = (bid >> 1) & 127, b = bid >> 8;
  const int w0 = seg << 6;

#pragma unroll
  for (int i = 0; i < 8; ++i) {
    const int idx = i * 512 + t;
    const int c = idx >> 6, o = idx & 63;
    *(unsigned short*)((char*)wts + swz(c, o * 2)) = f2bf(Wt[idx]);
  }

  const int wcol = w0 + lane;
  int aw = wcol - 2; if (aw < 0) aw = 0;        // clamped left-tap col
  int bw = wcol + 2; if (bw > 127) bw = 127;    // clamped right-tap col
  int rowoff[3];
  rowoff[0] = (y >= 2 ? y - 2 : 0) * WD;
  rowoff[1] = y * WD;
  rowoff[2] = (y <= 125 ? y + 2 : 127) * WD;

  const unsigned short* hb = h + (size_t)b * (NC * HWC);
  const int c0 = wv << 3;

  float S = 0.f, sumk[9], A[9], mreg[8];
#pragma unroll
  for (int k = 0; k < 9; ++k) { sumk[k] = 0.f; A[k] = 0.f; }

  // ---- Pass 1: partial S, sumk, A over this wave's 8 channels ----
#pragma unroll
  for (int i = 0; i < 8; ++i) {
    const unsigned short* hc = hb + (size_t)(c0 + i) * HWC;
    float tap[9];
#pragma unroll
    for (int r = 0; r < 3; ++r) {
      tap[3 * r + 0] = bf2f(hc[rowoff[r] + aw]);
      tap[3 * r + 1] = bf2f(hc[rowoff[r] + wcol]);
      tap[3 * r + 2] = bf2f(hc[rowoff[r] + bw]);
    }
    float m = 0.f;
#pragma unroll
    for (int k = 0; k < 9; ++k) m += tap[k];
    m *= (1.f / 9.f);
    mreg[i] = m;
    S += m * m;
#pragma unroll
    for (int k = 0; k < 9; ++k) { sumk[k] += tap[k]; A[k] += m * tap[k]; }
  }

  // ---- write 19 partials (stride 21: gcd(21,32)=1, conflict-free) ----
  {
    const int rb = t * 21;
    red[rb + 0] = S;
#pragma unroll
    for (int k = 0; k < 9; ++k) red[rb + 1 + k] = sumk[k];
#pragma unroll
    for (int k = 0; k < 9; ++k) red[rb + 10 + k] = A[k];
  }
  __syncthreads();

  // ---- combine: quantity q handled by wave q%8 (parallel across waves);
  //      final for (lane,q) lands in slot-0 cell red[lane*21+q] ----
  for (int q = wv; q < 19; q += 8) {
    float f = 0.f;
#pragma unroll
    for (int w = 0; w < 8; ++w) f += red[(w * 64 + lane) * 21 + q];
    red[lane * 21 + q] = f;
  }
  __syncthreads();

  // ---- every thread reads the 19 finals, computes Vk/T redundantly ----
  float Vk[9], T = 0.f;
  {
    const int rb = lane * 21;
    const float Sf = red[rb + 0];
#pragma unroll
    for (int k = 0; k < 9; ++k) {
      const float sk = red[rb + 1 + k];
      const float Ak = red[rb + 10 + k];
      const float nk = sk * (1.f / 64.f);
      Vk[k] = nk * (Ak / (3.f * nk * Sf + EPSV));
      T += Vk[k] * Vk[k];
    }
  }
  const float V4 = Vk[4];
  __syncthreads();   // everyone done reading red before UV overwrites it

  // ---- Pass 2: reload taps (L1-hot), B, U; write UV bf16 swizzled ----
#pragma unroll
  for (int i = 0; i < 8; i += 2) {
    unsigned short pk[2];
#pragma unroll
    for (int u = 0; u < 2; ++u) {
      const unsigned short* hc = hb + (size_t)(c0 + i + u) * HWC;
      float Bc = 0.f;
#pragma unroll
      for (int r = 0; r < 3; ++r) {
        Bc += bf2f(hc[rowoff[r] + aw])   * Vk[3 * r + 0];
        Bc += bf2f(hc[rowoff[r] + wcol]) * Vk[3 * r + 1];
        Bc += bf2f(hc[rowoff[r] + bw])   * Vk[3 * r + 2];
      }
      const float m = mreg[i + u];
      const float Uc = m * (Bc / (3.f * m * T + EPSV));
      pk[u] = f2bf(3.f * Uc * V4);
    }
    const unsigned w32 = (unsigned)pk[0] | ((unsigned)pk[1] << 16);
    *(unsigned*)((char*)uvb + swz(lane, (c0 + i) * 2)) = w32;
  }
  __syncthreads();

  // ---- Tail MFMA: wave wv -> M-tile (wv&3), N-tiles {2(wv>>2), +1} ----
  const int l15 = lane & 15, kg = lane >> 4;
  const int mtile = wv & 3, n0 = (wv >> 2) << 1;
  const int mrow = (mtile << 4) + l15;  // c_out row for A
  const bf16x8 a0 = *(const bf16x8*)((char*)wts + swz(mrow, kg * 16));
  const bf16x8 a1 = *(const bf16x8*)((char*)wts + swz(mrow, 64 + kg * 16));
  const f32x4 z = {0.f, 0.f, 0.f, 0.f};
  const size_t gb = (size_t)b * (NC * HWC) + (size_t)y * WD + w0;
#pragma unroll
  for (int nt = n0; nt < n0 + 2; ++nt) {
    const int px = (nt << 4) + l15;
    const bf16x8 b0 = *(const bf16x8*)((char*)uvb + swz(px, kg * 16));
    const bf16x8 b1 = *(const bf16x8*)((char*)uvb + swz(px, 64 + kg * 16));
    f32x4 acc = __builtin_amdgcn_mfma_f32_16x16x32_bf16(a0, b0, z, 0, 0, 0);
    acc = __builtin_amdgcn_mfma_f32_16x16x32_bf16(a1, b1, acc, 0, 0, 0);
#pragma unroll
    for (int j = 0; j < 4; ++j) {
      const int c2 = (mtile << 4) + kg * 4 + j;
      const size_t off = gb + (size_t)c2 * HWC + px;
      out[off] = acc[j] + x[off];
    }
  }
}

extern "C" void kernel_launch(void* const* d_in, const int* in_sizes, int n_in,
                              void* d_out, int out_size, void* d_ws, size_t ws_size,
                              hipStream_t stream) {
  const float* x  = (const float*)d_in[0];
  const float* Wh = (const float*)d_in[1];
  const float* Wt = (const float*)d_in[2];
  float* out = (float*)d_out;
  unsigned short* h = (unsigned short*)d_ws;  // h in bf16: 8.39 MB scratch

  k_head<<<1024, 256, 0, stream>>>(x, Wh, h);
  k_nmf_tail<<<1024, 512, 0, stream>>>(h, x, Wt, out);
}

// Round 8
// 29.218 us; speedup vs baseline: 2.8830x; 1.3022x over previous
//
#include <hip/hip_runtime.h>

#define HWC 16384      // H*W
#define WD  128
#define NC  64
#define EPSV 1e-6f

typedef __attribute__((ext_vector_type(8))) short bf16x8;
typedef __attribute__((ext_vector_type(4))) float f32x4;

__device__ __forceinline__ unsigned short f2bf(float f) {
  unsigned u = __builtin_bit_cast(unsigned, f);
  u = (u + 0x7FFFu + ((u >> 16) & 1u)) >> 16;   // RNE
  return (unsigned short)u;
}
__device__ __forceinline__ float bf2f(unsigned short h) {
  unsigned u = ((unsigned)h) << 16;
  return __builtin_bit_cast(float, u);
}
__device__ __forceinline__ float bfLo(unsigned pk) {   // low bf16 of packed pair
  return __builtin_bit_cast(float, pk << 16);
}
__device__ __forceinline__ float bfHi(unsigned pk) {   // high bf16 of packed pair
  return __builtin_bit_cast(float, pk & 0xFFFF0000u);
}
// XOR swizzle for [64][64] bf16 tiles (128 B rows): spreads b128 frag reads.
__device__ __forceinline__ int swz(int row, int colbytes) {
  return ((row << 7) + colbytes) ^ ((row & 7) << 4);
}

// ---------------- Kernel 1: head 1x1 conv (MFMA) + ReLU -> h bf16 ----------
// grid 1024 (b,y,seg): 64-px segment. 256 thr = 4 waves. (unchanged)
__global__ __launch_bounds__(256) void k_head(const float* __restrict__ x,
                                              const float* __restrict__ Wh,
                                              unsigned short* __restrict__ h) {
  __shared__ unsigned short whs[4096];  // Wh bf16 [o][c], swizzled
  __shared__ unsigned short xt[4096];   // x^T bf16 [px][c], swizzled
  const int t = threadIdx.x, lane = t & 63, wv = t >> 6;
  const int bid = blockIdx.x;
  const int seg = bid & 1, y = (bid >> 1) & 127, b = bid >> 8;
  const int w0 = seg << 6;

#pragma unroll
  for (int i = 0; i < 16; ++i) {
    const int idx = i * 256 + t;
    const int o = idx >> 6, c = idx & 63;
    *(unsigned short*)((char*)whs + swz(o, c * 2)) = f2bf(Wh[idx]);
  }
  {
    const float* xb = x + (size_t)b * (NC * HWC) + (size_t)y * WD + w0;
    const int c0 = wv << 4;
#pragma unroll
    for (int q = 0; q < 4; ++q) {
      unsigned long long pk = 0;
#pragma unroll
      for (int u = 0; u < 4; ++u) {
        const unsigned short v = f2bf(xb[(size_t)(c0 + q * 4 + u) * HWC + lane]);
        pk |= (unsigned long long)v << (16 * u);
      }
      *(unsigned long long*)((char*)xt + swz(lane, (c0 + q * 4) * 2)) = pk;
    }
  }
  __syncthreads();

  const int l15 = lane & 15, kg = lane >> 4;
  const int mrow = (wv << 4) + l15;
  const bf16x8 a0 = *(const bf16x8*)((char*)whs + swz(mrow, kg * 16));
  const bf16x8 a1 = *(const bf16x8*)((char*)whs + swz(mrow, 64 + kg * 16));
  const f32x4 z = {0.f, 0.f, 0.f, 0.f};
  unsigned short* hb = h + (size_t)b * (NC * HWC) + (size_t)y * WD + w0;
#pragma unroll
  for (int nt = 0; nt < 4; ++nt) {
    const int px = (nt << 4) + l15;
    const bf16x8 b0 = *(const bf16x8*)((char*)xt + swz(px, kg * 16));
    const bf16x8 b1 = *(const bf16x8*)((char*)xt + swz(px, 64 + kg * 16));
    f32x4 acc = __builtin_amdgcn_mfma_f32_16x16x32_bf16(a0, b0, z, 0, 0, 0);
    acc = __builtin_amdgcn_mfma_f32_16x16x32_bf16(a1, b1, acc, 0, 0, 0);
#pragma unroll
    for (int j = 0; j < 4; ++j) {
      const int o = (wv << 4) + kg * 4 + j;   // D: row=(lane>>4)*4+j, col=l15
      float v = acc[j];
      v = v > 0.f ? v : 0.f;
      hb[(size_t)o * HWC + px] = f2bf(v);
    }
  }
}

// ------- Kernel 2: fused NMF (reg-cached taps) + MFMA tail + residual ------
// grid 1024 (b,y,seg). 512 thr = 8 waves. lane = px (coalesced); wave wv owns
// channels [8wv,+8). Taps loaded ONCE (pass 1), kept packed bf16 in 40 VGPRs;
// pass 2 is pure VALU. Cross-wave reduce: 19 partials split across waves.
__global__ __launch_bounds__(512, 4) void k_nmf_tail(const unsigned short* __restrict__ h,
                                                     const float* __restrict__ x,
                                                     const float* __restrict__ Wt,
                                                     float* __restrict__ out) {
  __shared__ float red[512 * 21];          // 43008 B; unioned with uvb after use
  __shared__ unsigned short wts[4096];     // Wt bf16 [c][o], swizzled, 8192 B
  unsigned short* uvb = (unsigned short*)red;  // UV bf16 [px][o], swizzled

  const int t = threadIdx.x, lane = t & 63, wv = t >> 6;
  const int bid0 = blockIdx.x;
  const int bid = ((bid0 & 7) << 7) | (bid0 >> 3);  // XCD swizzle, bijective (1024%8==0)
  const int seg = bid & 1, y = (bid >> 1) & 127, b = bid >> 8;
  const int w0 = seg << 6;

#pragma unroll
  for (int i = 0; i < 8; ++i) {
    const int idx = i * 512 + t;
    const int c = idx >> 6, o = idx & 63;
    *(unsigned short*)((char*)wts + swz(c, o * 2)) = f2bf(Wt[idx]);
  }

  const int wcol = w0 + lane;
  int aw = wcol - 2; if (aw < 0) aw = 0;        // clamped left-tap col
  int bw = wcol + 2; if (bw > 127) bw = 127;    // clamped right-tap col
  int rowoff[3];
  rowoff[0] = (y >= 2 ? y - 2 : 0) * WD;
  rowoff[1] = y * WD;
  rowoff[2] = (y <= 125 ? y + 2 : 127) * WD;

  const unsigned short* hb = h + (size_t)b * (NC * HWC);
  const int c0 = wv << 3;

  float S = 0.f, sumk[9], A[9], mreg[8];
  unsigned tp[8][5];   // packed bf16 tap cache: [ch][(t0,t1)(t2,t3)(t4,t5)(t6,t7)(t8,-)]
#pragma unroll
  for (int k = 0; k < 9; ++k) { sumk[k] = 0.f; A[k] = 0.f; }

  // ---- Pass 1: load taps once, cache packed, accumulate partials ----
#pragma unroll
  for (int i = 0; i < 8; ++i) {
    const unsigned short* hc = hb + (size_t)(c0 + i) * HWC;
    unsigned short t9[9];
#pragma unroll
    for (int r = 0; r < 3; ++r) {
      t9[3 * r + 0] = hc[rowoff[r] + aw];
      t9[3 * r + 1] = hc[rowoff[r] + wcol];
      t9[3 * r + 2] = hc[rowoff[r] + bw];
    }
    tp[i][0] = (unsigned)t9[0] | ((unsigned)t9[1] << 16);
    tp[i][1] = (unsigned)t9[2] | ((unsigned)t9[3] << 16);
    tp[i][2] = (unsigned)t9[4] | ((unsigned)t9[5] << 16);
    tp[i][3] = (unsigned)t9[6] | ((unsigned)t9[7] << 16);
    tp[i][4] = (unsigned)t9[8];
    float tap[9];
#pragma unroll
    for (int k = 0; k < 9; ++k) tap[k] = bf2f(t9[k]);
    float m = 0.f;
#pragma unroll
    for (int k = 0; k < 9; ++k) m += tap[k];
    m *= (1.f / 9.f);
    mreg[i] = m;
    S += m * m;
#pragma unroll
    for (int k = 0; k < 9; ++k) { sumk[k] += tap[k]; A[k] += m * tap[k]; }
  }

  // ---- write 19 partials (stride 21: gcd(21,32)=1, conflict-free) ----
  {
    const int rb = t * 21;
    red[rb + 0] = S;
#pragma unroll
    for (int k = 0; k < 9; ++k) red[rb + 1 + k] = sumk[k];
#pragma unroll
    for (int k = 0; k < 9; ++k) red[rb + 10 + k] = A[k];
  }
  __syncthreads();

  // ---- combine: quantity q handled by wave q%8 (parallel across waves);
  //      final for (lane,q) lands in slot-0 cell red[lane*21+q] ----
  for (int q = wv; q < 19; q += 8) {
    float f = 0.f;
#pragma unroll
    for (int w = 0; w < 8; ++w) f += red[(w * 64 + lane) * 21 + q];
    red[lane * 21 + q] = f;
  }
  __syncthreads();

  // ---- every thread reads the 19 finals, computes Vk/T redundantly ----
  float Vk[9], T = 0.f;
  {
    const int rb = lane * 21;
    const float Sf = red[rb + 0];
#pragma unroll
    for (int k = 0; k < 9; ++k) {
      const float sk = red[rb + 1 + k];
      const float Ak = red[rb + 10 + k];
      const float nk = sk * (1.f / 64.f);
      Vk[k] = nk * (Ak / (3.f * nk * Sf + EPSV));
      T += Vk[k] * Vk[k];
    }
  }
  const float V4 = Vk[4];
  __syncthreads();   // everyone done reading red before UV overwrites it

  // ---- Pass 2: pure VALU from cached taps; write UV bf16 swizzled ----
#pragma unroll
  for (int i = 0; i < 8; i += 2) {
    unsigned short pk[2];
#pragma unroll
    for (int u = 0; u < 2; ++u) {
      float Bc = 0.f;
      Bc += bfLo(tp[i + u][0]) * Vk[0];
      Bc += bfHi(tp[i + u][0]) * Vk[1];
      Bc += bfLo(tp[i + u][1]) * Vk[2];
      Bc += bfHi(tp[i + u][1]) * Vk[3];
      Bc += bfLo(tp[i + u][2]) * Vk[4];
      Bc += bfHi(tp[i + u][2]) * Vk[5];
      Bc += bfLo(tp[i + u][3]) * Vk[6];
      Bc += bfHi(tp[i + u][3]) * Vk[7];
      Bc += bfLo(tp[i + u][4]) * Vk[8];
      const float m = mreg[i + u];
      const float Uc = m * (Bc / (3.f * m * T + EPSV));
      pk[u] = f2bf(3.f * Uc * V4);
    }
    const unsigned w32 = (unsigned)pk[0] | ((unsigned)pk[1] << 16);
    *(unsigned*)((char*)uvb + swz(lane, (c0 + i) * 2)) = w32;
  }
  __syncthreads();

  // ---- Tail MFMA: wave wv -> M-tile (wv&3), N-tiles {2(wv>>2), +1} ----
  const int l15 = lane & 15, kg = lane >> 4;
  const int mtile = wv & 3, n0 = (wv >> 2) << 1;
  const int mrow = (mtile << 4) + l15;  // c_out row for A
  const bf16x8 a0 = *(const bf16x8*)((char*)wts + swz(mrow, kg * 16));
  const bf16x8 a1 = *(const bf16x8*)((char*)wts + swz(mrow, 64 + kg * 16));
  const f32x4 z = {0.f, 0.f, 0.f, 0.f};
  const size_t gb = (size_t)b * (NC * HWC) + (size_t)y * WD + w0;
#pragma unroll
  for (int nt = n0; nt < n0 + 2; ++nt) {
    const int px = (nt << 4) + l15;
    const bf16x8 b0 = *(const bf16x8*)((char*)uvb + swz(px, kg * 16));
    const bf16x8 b1 = *(const bf16x8*)((char*)uvb + swz(px, 64 + kg * 16));
    f32x4 acc = __builtin_amdgcn_mfma_f32_16x16x32_bf16(a0, b0, z, 0, 0, 0);
    acc = __builtin_amdgcn_mfma_f32_16x16x32_bf16(a1, b1, acc, 0, 0, 0);
#pragma unroll
    for (int j = 0; j < 4; ++j) {
      const int c2 = (mtile << 4) + kg * 4 + j;
      const size_t off = gb + (size_t)c2 * HWC + px;
      out[off] = acc[j] + x[off];
    }
  }
}

extern "C" void kernel_launch(void* const* d_in, const int* in_sizes, int n_in,
                              void* d_out, int out_size, void* d_ws, size_t ws_size,
                              hipStream_t stream) {
  const float* x  = (const float*)d_in[0];
  const float* Wh = (const float*)d_in[1];
  const float* Wt = (const float*)d_in[2];
  float* out = (float*)d_out;
  unsigned short* h = (unsigned short*)d_ws;  // h in bf16: 8.39 MB scratch

  k_head<<<1024, 256, 0, stream>>>(x, Wh, h);
  k_nmf_tail<<<1024, 512, 0, stream>>>(h, x, Wt, out);
}

// Round 9
// 28.101 us; speedup vs baseline: 2.9976x; 1.0397x over previous
//
#include <hip/hip_runtime.h>

#define HWC 16384      // H*W
#define WD  128
#define NC  64
#define EPSV 1e-6f

typedef __attribute__((ext_vector_type(8))) short bf16x8;
typedef __attribute__((ext_vector_type(4))) float f32x4;

__device__ __forceinline__ unsigned short f2bf(float f) {
  unsigned u = __builtin_bit_cast(unsigned, f);
  u = (u + 0x7FFFu + ((u >> 16) & 1u)) >> 16;   // RNE
  return (unsigned short)u;
}
__device__ __forceinline__ float bf2f(unsigned short h) {
  return __builtin_bit_cast(float, ((unsigned)h) << 16);
}
__device__ __forceinline__ float bfLo(unsigned pk) { return __builtin_bit_cast(float, pk << 16); }
__device__ __forceinline__ float bfHi(unsigned pk) { return __builtin_bit_cast(float, pk & 0xFFFF0000u); }
// XOR swizzle for 128-B-row bf16 tiles.
__device__ __forceinline__ int swz(int row, int colbytes) {
  return ((row << 7) + colbytes) ^ ((row & 7) << 4);
}
__device__ __forceinline__ bf16x8 pack8(float4 a, float4 b) {
  bf16x8 r;
  r[0] = (short)f2bf(a.x); r[1] = (short)f2bf(a.y);
  r[2] = (short)f2bf(a.z); r[3] = (short)f2bf(a.w);
  r[4] = (short)f2bf(b.x); r[5] = (short)f2bf(b.y);
  r[6] = (short)f2bf(b.z); r[7] = (short)f2bf(b.w);
  return r;
}

// Fully fused: head 1x1 conv (MFMA, 3 tap-rows x 68 tap-cols into LDS) ->
// per-pixel rank-collapsed NMF (reg-cached taps) -> tail 1x1 conv (MFMA)
// + residual. grid 1024 (b,y,seg); 512 thr = 8 waves.
__global__ __launch_bounds__(512, 4) void k_fused(const float* __restrict__ x,
                                                  const float* __restrict__ Wh,
                                                  const float* __restrict__ Wt,
                                                  float* __restrict__ out) {
  __shared__ __align__(16) char smem[53760];
  unsigned short* xt = (unsigned short*)smem;            // [208 sites][64 c] bf16 swz, 26624 B
  unsigned short* hl = (unsigned short*)(smem + 26624);  // [64 c][212] bf16, 27136 B
  float* red = (float*)smem;                             // overlay (43008 B), after hl dead
  unsigned short* uvb = (unsigned short*)smem;           // overlay (8192 B), after red dead

  const int t = threadIdx.x, lane = t & 63, wv = t >> 6;
  const int bid0 = blockIdx.x;
  const int bid = ((bid0 & 7) << 7) | (bid0 >> 3);  // XCD swizzle, bijective (1024%8==0)
  const int seg = bid & 1, y = (bid >> 1) & 127, b = bid >> 8;
  const int w0 = seg << 6;
  const int c0 = wv << 3;
  const int l15 = lane & 15, kg = lane >> 4;
  const int mt = wv & 3;
  const int mrow = (mt << 4) + l15;

  int gy[3];
  gy[0] = y >= 2 ? y - 2 : 0;
  gy[1] = y;
  gy[2] = y <= 125 ? y + 2 : 127;

  const float* xb = x + (size_t)b * (NC * HWC);

  // ---- head A fragments gathered from global Wh (L2-resident) ----
  bf16x8 ha0, ha1;
  {
    const float* wr = Wh + mrow * 64 + kg * 8;
    ha0 = pack8(*(const float4*)wr, *(const float4*)(wr + 4));
    ha1 = pack8(*(const float4*)(wr + 32), *(const float4*)(wr + 36));
  }

  // ---- stage xt: site s = r*68+i <-> (tap row gy[r], col clamp(w0-2+i)) ----
  {
    int colm = w0 - 2 + lane; if (colm < 0) colm = 0;
#pragma unroll
    for (int r = 0; r < 3; ++r) {
      const float* xr = xb + gy[r] * WD;
      const int srow = r * 68 + lane;
#pragma unroll
      for (int q = 0; q < 2; ++q) {
        unsigned long long pk = 0;
#pragma unroll
        for (int u = 0; u < 4; ++u)
          pk |= (unsigned long long)f2bf(xr[(size_t)(c0 + q * 4 + u) * HWC + colm]) << (16 * u);
        *(unsigned long long*)((char*)xt + swz(srow, (c0 + q * 4) * 2)) = pk;
      }
    }
    if (lane < 12) {   // extra cols i=64..67: (r = lane>>2, e = lane&3)
      const int re = lane >> 2, e = lane & 3;
      int cole = w0 + 62 + e; if (cole > 127) cole = 127;
      const float* xr = xb + gy[re] * WD;
      const int srow = re * 68 + 64 + e;
#pragma unroll
      for (int q = 0; q < 2; ++q) {
        unsigned long long pk = 0;
#pragma unroll
        for (int u = 0; u < 4; ++u)
          pk |= (unsigned long long)f2bf(xr[(size_t)(c0 + q * 4 + u) * HWC + cole]) << (16 * u);
        *(unsigned long long*)((char*)xt + swz(srow, (c0 + q * 4) * 2)) = pk;
      }
    }
  }
  __syncthreads();

  // ---- head MFMA: 13 N-tiles (208 sites) x 4 M-tiles; ReLU -> hl ----
  {
    const int ntBeg = (wv >> 2) ? 7 : 0;
    const int ntEnd = (wv >> 2) ? 13 : 7;
    const f32x4 z = {0.f, 0.f, 0.f, 0.f};
    for (int nt = ntBeg; nt < ntEnd; ++nt) {
      const int s = (nt << 4) + l15;
      const bf16x8 b0 = *(const bf16x8*)((char*)xt + swz(s, kg * 16));
      const bf16x8 b1 = *(const bf16x8*)((char*)xt + swz(s, 64 + kg * 16));
      f32x4 acc = __builtin_amdgcn_mfma_f32_16x16x32_bf16(ha0, b0, z, 0, 0, 0);
      acc = __builtin_amdgcn_mfma_f32_16x16x32_bf16(ha1, b1, acc, 0, 0, 0);
#pragma unroll
      for (int j = 0; j < 4; ++j) {
        const int c2 = (mt << 4) + kg * 4 + j;
        float v = acc[j];
        v = v > 0.f ? v : 0.f;
        hl[c2 * 212 + s] = f2bf(v);   // stride 212: kg-groups land on disjoint banks
      }
    }
  }
  __syncthreads();

  // ---- NMF pass 1: taps from hl (conflict-free contiguous reads), cache in regs ----
  float S = 0.f, sumk[9], A[9], mreg[8];
  unsigned tp[8][5];   // packed bf16 tap cache
#pragma unroll
  for (int k = 0; k < 9; ++k) { sumk[k] = 0.f; A[k] = 0.f; }
#pragma unroll
  for (int i = 0; i < 8; ++i) {
    const int hb2 = (c0 + i) * 212 + lane;   // lane = px; tap col k -> +2k, row r -> +68r
    unsigned short t9[9];
#pragma unroll
    for (int r = 0; r < 3; ++r) {
#pragma unroll
      for (int k = 0; k < 3; ++k) t9[3 * r + k] = hl[hb2 + r * 68 + 2 * k];
    }
    tp[i][0] = (unsigned)t9[0] | ((unsigned)t9[1] << 16);
    tp[i][1] = (unsigned)t9[2] | ((unsigned)t9[3] << 16);
    tp[i][2] = (unsigned)t9[4] | ((unsigned)t9[5] << 16);
    tp[i][3] = (unsigned)t9[6] | ((unsigned)t9[7] << 16);
    tp[i][4] = (unsigned)t9[8];
    float tap[9];
#pragma unroll
    for (int k = 0; k < 9; ++k) tap[k] = bf2f(t9[k]);
    float m = 0.f;
#pragma unroll
    for (int k = 0; k < 9; ++k) m += tap[k];
    m *= (1.f / 9.f);
    mreg[i] = m;
    S += m * m;
#pragma unroll
    for (int k = 0; k < 9; ++k) { sumk[k] += tap[k]; A[k] += m * tap[k]; }
  }
  __syncthreads();   // all reads of hl/xt done -> red overlay is safe

  // ---- write 19 partials (stride 21: conflict-free) ----
  {
    const int rb = t * 21;
    red[rb + 0] = S;
#pragma unroll
    for (int k = 0; k < 9; ++k) red[rb + 1 + k] = sumk[k];
#pragma unroll
    for (int k = 0; k < 9; ++k) red[rb + 10 + k] = A[k];
  }
  __syncthreads();

  // ---- combine: quantity q by wave q%8; finals land in red[lane*21+q] ----
  for (int q = wv; q < 19; q += 8) {
    float f = 0.f;
#pragma unroll
    for (int w = 0; w < 8; ++w) f += red[(w * 64 + lane) * 21 + q];
    red[lane * 21 + q] = f;
  }
  __syncthreads();

  // ---- every thread reads the 19 finals, computes Vk/T redundantly ----
  float Vk[9], T = 0.f;
  {
    const int rb = lane * 21;
    const float Sf = red[rb + 0];
#pragma unroll
    for (int k = 0; k < 9; ++k) {
      const float sk = red[rb + 1 + k];
      const float Ak = red[rb + 10 + k];
      const float nk = sk * (1.f / 64.f);
      Vk[k] = nk * (Ak / (3.f * nk * Sf + EPSV));
      T += Vk[k] * Vk[k];
    }
  }
  const float V4 = Vk[4];
  __syncthreads();   // finals read done -> uvb overlay safe

  // ---- tail A fragments gathered from global Wt (hides under pass 2) ----
  bf16x8 ta0, ta1;
  {
    const float* wr = Wt + mrow * 64 + kg * 8;
    ta0 = pack8(*(const float4*)wr, *(const float4*)(wr + 4));
    ta1 = pack8(*(const float4*)(wr + 32), *(const float4*)(wr + 36));
  }

  // ---- pass 2: pure VALU from cached taps; write UV bf16 swizzled ----
#pragma unroll
  for (int i = 0; i < 8; i += 2) {
    unsigned short pk[2];
#pragma unroll
    for (int u = 0; u < 2; ++u) {
      float Bc = 0.f;
      Bc += bfLo(tp[i + u][0]) * Vk[0];
      Bc += bfHi(tp[i + u][0]) * Vk[1];
      Bc += bfLo(tp[i + u][1]) * Vk[2];
      Bc += bfHi(tp[i + u][1]) * Vk[3];
      Bc += bfLo(tp[i + u][2]) * Vk[4];
      Bc += bfHi(tp[i + u][2]) * Vk[5];
      Bc += bfLo(tp[i + u][3]) * Vk[6];
      Bc += bfHi(tp[i + u][3]) * Vk[7];
      Bc += bfLo(tp[i + u][4]) * Vk[8];
      const float m = mreg[i + u];
      const float Uc = m * (Bc / (3.f * m * T + EPSV));
      pk[u] = f2bf(3.f * Uc * V4);
    }
    const unsigned w32 = (unsigned)pk[0] | ((unsigned)pk[1] << 16);
    *(unsigned*)((char*)uvb + swz(lane, (c0 + i) * 2)) = w32;
  }
  __syncthreads();

  // ---- tail MFMA: M-tile mt, N-tiles {2*(wv>>2), +1}; + residual ----
  const int n0 = (wv >> 2) << 1;
  const f32x4 z = {0.f, 0.f, 0.f, 0.f};
  const size_t gb = (size_t)b * (NC * HWC) + (size_t)y * WD + w0;
#pragma unroll
  for (int nt = n0; nt < n0 + 2; ++nt) {
    const int px = (nt << 4) + l15;
    const bf16x8 b0 = *(const bf16x8*)((char*)uvb + swz(px, kg * 16));
    const bf16x8 b1 = *(const bf16x8*)((char*)uvb + swz(px, 64 + kg * 16));
    f32x4 acc = __builtin_amdgcn_mfma_f32_16x16x32_bf16(ta0, b0, z, 0, 0, 0);
    acc = __builtin_amdgcn_mfma_f32_16x16x32_bf16(ta1, b1, acc, 0, 0, 0);
#pragma unroll
    for (int j = 0; j < 4; ++j) {
      const int c2 = (mt << 4) + kg * 4 + j;
      const size_t off = gb + (size_t)c2 * HWC + px;
      out[off] = acc[j] + x[off];
    }
  }
}

extern "C" void kernel_launch(void* const* d_in, const int* in_sizes, int n_in,
                              void* d_out, int out_size, void* d_ws, size_t ws_size,
                              hipStream_t stream) {
  const float* x  = (const float*)d_in[0];
  const float* Wh = (const float*)d_in[1];
  const float* Wt = (const float*)d_in[2];
  float* out = (float*)d_out;

  k_fused<<<1024, 512, 0, stream>>>(x, Wh, Wt, out);
}

// Round 10
// 27.124 us; speedup vs baseline: 3.1056x; 1.0360x over previous
//
#include <hip/hip_runtime.h>

#define HWC 16384      // H*W
#define WD  128
#define NC  64
#define EPSV 1e-6f

typedef __attribute__((ext_vector_type(8))) short bf16x8;
typedef __attribute__((ext_vector_type(4))) float f32x4;
typedef __attribute__((ext_vector_type(4))) unsigned int u32x4;

__device__ __forceinline__ unsigned short f2bf(float f) {
  unsigned u = __builtin_bit_cast(unsigned, f);
  u = (u + 0x7FFFu + ((u >> 16) & 1u)) >> 16;   // RNE
  return (unsigned short)u;
}
__device__ __forceinline__ float bfLo(unsigned pk) { return __builtin_bit_cast(float, pk << 16); }
__device__ __forceinline__ float bfHi(unsigned pk) { return __builtin_bit_cast(float, pk & 0xFFFF0000u); }
// XOR swizzle for 128-B-row bf16 tiles.
__device__ __forceinline__ int swz(int row, int colbytes) {
  return ((row << 7) + colbytes) ^ ((row & 7) << 4);
}
__device__ __forceinline__ bf16x8 pack8(float4 a, float4 b) {
  bf16x8 r;
  r[0] = (short)f2bf(a.x); r[1] = (short)f2bf(a.y);
  r[2] = (short)f2bf(a.z); r[3] = (short)f2bf(a.w);
  r[4] = (short)f2bf(b.x); r[5] = (short)f2bf(b.y);
  r[6] = (short)f2bf(b.z); r[7] = (short)f2bf(b.w);
  return r;
}

// Fully fused head->NMF->tail. grid 1024 (b,y,seg); 512 thr = 8 waves.
// xt, hl both [site][ch] bf16 swizzled -> all hot LDS traffic is b128.
__global__ __launch_bounds__(512, 4) void k_fused(const float* __restrict__ x,
                                                  const float* __restrict__ Wh,
                                                  const float* __restrict__ Wt,
                                                  float* __restrict__ out) {
  __shared__ __align__(16) char smem[53248];
  unsigned short* xt = (unsigned short*)smem;            // [208 sites][64 c], 26624 B
  unsigned short* hl = (unsigned short*)(smem + 26624);  // [208 sites][64 o], 26624 B
  float* red = (float*)smem;                             // overlay: 512 cells x 22 f32 (45056 B)
  unsigned short* uvb = (unsigned short*)smem;           // overlay: [64 px][64 o] (8192 B)

  const int t = threadIdx.x, lane = t & 63, wv = t >> 6;
  const int bid0 = blockIdx.x;
  const int bid = ((bid0 & 7) << 7) | (bid0 >> 3);  // XCD swizzle, bijective (1024%8==0)
  const int seg = bid & 1, y = (bid >> 1) & 127, b = bid >> 8;
  const int w0 = seg << 6;
  const int c0 = wv << 3;
  const int l15 = lane & 15, kg = lane >> 4;
  const int mt = wv & 3;
  const int mrow = (mt << 4) + l15;

  int gy[3];
  gy[0] = y >= 2 ? y - 2 : 0;
  gy[1] = y;
  gy[2] = y <= 125 ? y + 2 : 127;

  const float* xb = x + (size_t)b * (NC * HWC);

  // ---- head A fragments from global Wh (L2-resident) ----
  bf16x8 ha0, ha1;
  {
    const float* wr = Wh + mrow * 64 + kg * 8;
    ha0 = pack8(*(const float4*)wr, *(const float4*)(wr + 4));
    ha1 = pack8(*(const float4*)(wr + 32), *(const float4*)(wr + 36));
  }

  // ---- stage xt[site][ch]: site s = r*68+i <-> (row gy[r], col clamp(w0-2+i)) ----
  {
    int colm = w0 - 2 + lane; if (colm < 0) colm = 0;
#pragma unroll
    for (int r = 0; r < 3; ++r) {
      const float* xr = xb + gy[r] * WD + colm;
      bf16x8 v;
#pragma unroll
      for (int u = 0; u < 8; ++u) v[u] = (short)f2bf(xr[(size_t)(c0 + u) * HWC]);
      *(bf16x8*)((char*)xt + swz(r * 68 + lane, c0 * 2)) = v;
    }
    if (lane < 12) {   // extra cols i=64..67
      const int re = lane >> 2, e = lane & 3;
      int cole = w0 + 62 + e; if (cole > 127) cole = 127;
      const float* xr = xb + gy[re] * WD + cole;
      bf16x8 v;
#pragma unroll
      for (int u = 0; u < 8; ++u) v[u] = (short)f2bf(xr[(size_t)(c0 + u) * HWC]);
      *(bf16x8*)((char*)xt + swz(re * 68 + 64 + e, c0 * 2)) = v;
    }
  }
  __syncthreads();

  // ---- head MFMA: 13 N-tiles x 4 M-tiles; ReLU; packed uint2 write to hl ----
  {
    const int ntBeg = (wv >> 2) ? 7 : 0;
    const int ntEnd = (wv >> 2) ? 13 : 7;
    const f32x4 z = {0.f, 0.f, 0.f, 0.f};
    for (int nt = ntBeg; nt < ntEnd; ++nt) {
      const int s = (nt << 4) + l15;
      const bf16x8 b0 = *(const bf16x8*)((char*)xt + swz(s, kg * 16));
      const bf16x8 b1 = *(const bf16x8*)((char*)xt + swz(s, 64 + kg * 16));
      f32x4 acc = __builtin_amdgcn_mfma_f32_16x16x32_bf16(ha0, b0, z, 0, 0, 0);
      acc = __builtin_amdgcn_mfma_f32_16x16x32_bf16(ha1, b1, acc, 0, 0, 0);
      const float v0 = acc[0] > 0.f ? acc[0] : 0.f;
      const float v1 = acc[1] > 0.f ? acc[1] : 0.f;
      const float v2 = acc[2] > 0.f ? acc[2] : 0.f;
      const float v3 = acc[3] > 0.f ? acc[3] : 0.f;
      uint2 pk2;
      pk2.x = (unsigned)f2bf(v0) | ((unsigned)f2bf(v1) << 16);
      pk2.y = (unsigned)f2bf(v2) | ((unsigned)f2bf(v3) << 16);
      // D row = o = mt*16+kg*4+j (4 consecutive channels), col = site s
      *(uint2*)((char*)hl + swz(s, (mt * 16 + kg * 4) * 2)) = pk2;
    }
  }
  __syncthreads();

  // ---- NMF pass 1: 9 x ds_read_b128 (8 ch per read); tap cache = the reads ----
  const int pl = lane;   // px
  u32x4 tap[9];
#pragma unroll
  for (int r = 0; r < 3; ++r)
#pragma unroll
    for (int kc = 0; kc < 3; ++kc)
      tap[r * 3 + kc] = *(const u32x4*)((char*)hl + swz(r * 68 + pl + 2 * kc, c0 * 2));

  float S = 0.f, sumk[9], A[9], mreg[8];
#pragma unroll
  for (int k = 0; k < 9; ++k) { sumk[k] = 0.f; A[k] = 0.f; }
#pragma unroll
  for (int c = 0; c < 8; ++c) {
    float tc[9];
#pragma unroll
    for (int k = 0; k < 9; ++k) {
      const unsigned w32 = tap[k][c >> 1];
      tc[k] = (c & 1) ? bfHi(w32) : bfLo(w32);
    }
    float m = 0.f;
#pragma unroll
    for (int k = 0; k < 9; ++k) m += tc[k];
    m *= (1.f / 9.f);
    mreg[c] = m;
    S += m * m;
#pragma unroll
    for (int k = 0; k < 9; ++k) { sumk[k] += tc[k]; A[k] += m * tc[k]; }
  }
  __syncthreads();   // all hl reads done -> red overlay safe

  // ---- write 19 partials as float2 pairs (stride-22 cells, 8-B aligned) ----
  {
    float2* cell = (float2*)&red[t * 22];
    cell[0] = make_float2(S, sumk[0]);
    cell[1] = make_float2(sumk[1], sumk[2]);
    cell[2] = make_float2(sumk[3], sumk[4]);
    cell[3] = make_float2(sumk[5], sumk[6]);
    cell[4] = make_float2(sumk[7], sumk[8]);
    cell[5] = make_float2(A[0], A[1]);
    cell[6] = make_float2(A[2], A[3]);
    cell[7] = make_float2(A[4], A[5]);
    cell[8] = make_float2(A[6], A[7]);
    red[t * 22 + 18] = A[8];
  }
  __syncthreads();

  // ---- combine pair-slot p by wave p%8; finals land in cell[lane] ----
  for (int p = wv; p < 10; p += 8) {
    float2 f = {0.f, 0.f};
#pragma unroll
    for (int w2 = 0; w2 < 8; ++w2) {
      const float2 g = *(const float2*)&red[(w2 * 64 + lane) * 22 + 2 * p];
      f.x += g.x; f.y += g.y;
    }
    *(float2*)&red[lane * 22 + 2 * p] = f;   // p=9: .y is never-read pad
  }
  __syncthreads();

  // ---- every thread reads 10 float2 finals, computes Vk/T ----
  float Vk[9], T = 0.f;
  {
    const float2* cell = (const float2*)&red[lane * 22];
    const float2 d0 = cell[0], d1 = cell[1], d2 = cell[2], d3 = cell[3], d4 = cell[4];
    const float2 d5 = cell[5], d6 = cell[6], d7 = cell[7], d8 = cell[8];
    const float a8 = red[lane * 22 + 18];
    const float Sf = d0.x;
    const float sk[9] = {d0.y, d1.x, d1.y, d2.x, d2.y, d3.x, d3.y, d4.x, d4.y};
    const float Ak[9] = {d5.x, d5.y, d6.x, d6.y, d7.x, d7.y, d8.x, d8.y, a8};
#pragma unroll
    for (int k = 0; k < 9; ++k) {
      const float nk = sk[k] * (1.f / 64.f);
      Vk[k] = nk * (Ak[k] / (3.f * nk * Sf + EPSV));
      T += Vk[k] * Vk[k];
    }
  }
  const float V4 = Vk[4];
  __syncthreads();   // red reads done -> uvb overlay safe

  // ---- tail A fragments from global Wt (hides under pass 2) ----
  bf16x8 ta0, ta1;
  {
    const float* wr = Wt + mrow * 64 + kg * 8;
    ta0 = pack8(*(const float4*)wr, *(const float4*)(wr + 4));
    ta1 = pack8(*(const float4*)(wr + 32), *(const float4*)(wr + 36));
  }

  // ---- pass 2: pure VALU from cached taps; single b128 UV write ----
  {
    bf16x8 vv;
#pragma unroll
    for (int c = 0; c < 8; ++c) {
      float Bc = 0.f;
#pragma unroll
      for (int k = 0; k < 9; ++k) {
        const unsigned w32 = tap[k][c >> 1];
        const float tk = (c & 1) ? bfHi(w32) : bfLo(w32);
        Bc += tk * Vk[k];
      }
      const float m = mreg[c];
      const float Uc = m * (Bc / (3.f * m * T + EPSV));
      vv[c] = (short)f2bf(3.f * Uc * V4);
    }
    *(bf16x8*)((char*)uvb + swz(pl, c0 * 2)) = vv;   // [px][o]
  }
  __syncthreads();

  // ---- tail MFMA: M-tile mt, N-tiles {2*(wv>>2), +1}; + residual ----
  const int n0 = (wv >> 2) << 1;
  const f32x4 z2 = {0.f, 0.f, 0.f, 0.f};
  const size_t gb = (size_t)b * (NC * HWC) + (size_t)y * WD + w0;
#pragma unroll
  for (int nt = n0; nt < n0 + 2; ++nt) {
    const int px = (nt << 4) + l15;
    const bf16x8 b0 = *(const bf16x8*)((char*)uvb + swz(px, kg * 16));
    const bf16x8 b1 = *(const bf16x8*)((char*)uvb + swz(px, 64 + kg * 16));
    f32x4 acc = __builtin_amdgcn_mfma_f32_16x16x32_bf16(ta0, b0, z2, 0, 0, 0);
    acc = __builtin_amdgcn_mfma_f32_16x16x32_bf16(ta1, b1, acc, 0, 0, 0);
#pragma unroll
    for (int j = 0; j < 4; ++j) {
      const int c2 = (mt << 4) + kg * 4 + j;
      const size_t off = gb + (size_t)c2 * HWC + px;
      out[off] = acc[j] + x[off];
    }
  }
}

extern "C" void kernel_launch(void* const* d_in, const int* in_sizes, int n_in,
                              void* d_out, int out_size, void* d_ws, size_t ws_size,
                              hipStream_t stream) {
  const float* x  = (const float*)d_in[0];
  const float* Wh = (const float*)d_in[1];
  const float* Wt = (const float*)d_in[2];
  float* out = (float*)d_out;

  k_fused<<<1024, 512, 0, stream>>>(x, Wh, Wt, out);
}